// Round 8
// baseline (334.092 us; speedup 1.0000x reference)
//
#include <hip/hip_runtime.h>
#include <hip/hip_bf16.h>
#include <stdint.h>

// MozafariMNIST2018 forward. B=4096, T=15, HW=784, F1=500, F3=10.
// Output layout (float32, concatenated):
//   spk1 [4096*15*500] @ 0
//   thr1 [4096*15*500] @ 30720000
//   pot3 [4096*15*10]  @ 61440000
//   cls  [4096]        @ 62054400
//
// Identity: inp[b,t,p] = (t0[b,p] <= t), t0 = 15 - sum_t inp (4 bits).
// k_main structure (R8): block = 4 waves, ONE rowTile (64 rows) x 256 f
// (wave-split). Per K-step: A rebuilt from t0 nibbles ONCE into a 4KB LDS
// tile (shared by all 4 waves -> rebuild VALU /4 vs R7), B staged by
// global_load_lds (16KB, L2-resident w1frag), 16 MFMA/wave, one barrier.
// LDS 40KB double-buffered, ~100 VGPR -> 4 blocks/CU for cross-block
// latency overlap. fp32 acc + exact fp32 fixup for |p-THR|<0.05.

typedef _Float16     f16x8 __attribute__((ext_vector_type(8)));
typedef float        f32x4 __attribute__((ext_vector_type(4)));
typedef unsigned int u32x4 __attribute__((ext_vector_type(4)));

typedef __attribute__((address_space(3))) char        lds_char_t;
typedef const __attribute__((address_space(1))) char  gbl_char_t;

#define GLL16(gsrc, ldst) \
  __builtin_amdgcn_global_load_lds((gbl_char_t*)(gsrc), (lds_char_t*)(ldst), 16, 0, 0)

#define CONV1_T   26.3424f
#define FIX_DELTA 0.05f
#define KDIM 784
#define F1   500

// ------------------------------------------------------------------
// k_t0: t0nib[b][p] (4-bit) = 15 - sum_t inp[b,t,p]; pad p>=784 -> 15.
// 400 B per batch row (100 dwords).
// ------------------------------------------------------------------
__global__ __launch_bounds__(256)
void k_t0(const float* __restrict__ inp, unsigned int* __restrict__ t0nib)
{
    const int gid = blockIdx.x * 256 + threadIdx.x;   // < 409600
    const int b   = gid / 100;
    const int p8  = gid % 100;
    if (p8 >= 98) { t0nib[gid] = 0xFFFFFFFFu; return; }

    const float* base = inp + (size_t)b * 11760 + p8 * 8;
    float cnt[8];
    #pragma unroll
    for (int e = 0; e < 8; ++e) cnt[e] = 0.f;
    #pragma unroll
    for (int t = 0; t < 15; ++t) {
        const f32x4 v0 = *(const f32x4*)(base + t * 784);
        const f32x4 v1 = *(const f32x4*)(base + t * 784 + 4);
        #pragma unroll
        for (int e = 0; e < 4; ++e) { cnt[e] += v0[e]; cnt[e + 4] += v1[e]; }
    }
    unsigned int d = 0;
    #pragma unroll
    for (int e = 0; e < 8; ++e) {
        const unsigned int t0 = 15u - (unsigned int)cnt[e];   // 0..14
        d |= (t0 & 15u) << (4 * e);
    }
    t0nib[gid] = d;
}

// ------------------------------------------------------------------
// k_prep: w1 -> f16 w1frag in GLL16-ready B-fragment order.
// Byte layout: fblk*409600 + ks*16384 + wid*4096 + i*1024 + lane*16,
// lane=(kg*16+lr), element e: B[k=ks*32+kg*8+e][f=fblk*256+wid*64+i*16+lr].
// ------------------------------------------------------------------
__global__ __launch_bounds__(256)
void k_prep(const float* __restrict__ w1, _Float16* __restrict__ w1frag)
{
    const int gid  = blockIdx.x * 256 + threadIdx.x;   // < 51200
    const int lane = gid & 63;
    const int i    = (gid >> 6) & 3;
    const int wid  = (gid >> 8) & 3;
    const int ks   = (gid >> 10) % 25;
    const int fblk = gid / 25600;
    const int lr   = lane & 15;
    const int kg   = lane >> 4;
    const int f    = fblk * 256 + wid * 64 + i * 16 + lr;

    f16x8 v;
    #pragma unroll
    for (int e = 0; e < 8; ++e) {
        const int k = ks * 32 + kg * 8 + e;
        v[e] = (f < F1 && k < KDIM) ? (_Float16)w1[f * KDIM + k] : (_Float16)0.f;
    }
    *(f16x8*)(w1frag + (size_t)gid * 8) = v;
}

// exact fp32 recompute for near-threshold elements (rare)
__device__ __attribute__((noinline))
float fix_dot_t0(const unsigned char* __restrict__ nib,
                 const float* __restrict__ w, int t)
{
    float s0 = 0.f, s1 = 0.f, s2 = 0.f, s3 = 0.f;
    for (int k = 0; k < KDIM; k += 4) {
        const unsigned int b0 = nib[k >> 1];
        const unsigned int b1 = nib[(k >> 1) + 1];
        const float a0 = ((int)(b0 & 15u) <= t) ? 1.f : 0.f;
        const float a1 = ((int)(b0 >> 4)  <= t) ? 1.f : 0.f;
        const float a2 = ((int)(b1 & 15u) <= t) ? 1.f : 0.f;
        const float a3 = ((int)(b1 >> 4)  <= t) ? 1.f : 0.f;
        s0 = fmaf(a0, w[k],     s0);
        s1 = fmaf(a1, w[k + 1], s1);
        s2 = fmaf(a2, w[k + 2], s2);
        s3 = fmaf(a3, w[k + 3], s3);
    }
    return (s0 + s1) + (s2 + s3);
}

// rebuild 8 spike halfs from a t0 nibble dword: a[e] = (nib_e <= t)
__device__ __forceinline__
f16x8 rebuild_a(unsigned int d, int t)
{
    u32x4 br;
    #pragma unroll
    for (int h = 0; h < 4; ++h) {
        const unsigned int n0 = (d >> (8 * h))     & 15u;
        const unsigned int n1 = (d >> (8 * h + 4)) & 15u;
        br[h] = (n0 <= (unsigned)t ? 0x3C00u     : 0u)
              | (n1 <= (unsigned)t ? 0x3C000000u : 0u);
    }
    return __builtin_bit_cast(f16x8, br);
}

// ------------------------------------------------------------------
// k_main: block = 64 rows x 256 f, 4 waves (wave wid owns f-slice
// wid*64..+63). A-tile rebuilt once/block/K-step into LDS; B via GLL16.
// LDS: bufA 2x4KB @0, bufB 2x16KB @8192. One barrier per K-step.
// grid: 1920 = 960 rowTiles x 2 fblks (XCD-paired).
// ------------------------------------------------------------------
__global__ __launch_bounds__(256)
void k_main(const float* __restrict__ w1,
            const unsigned char* __restrict__ t0nib,
            const _Float16* __restrict__ w1frag,
            float* __restrict__ spk1, float* __restrict__ thr1)
{
    __shared__ char smem[40960];

    const int tid  = threadIdx.x;
    const int lane = tid & 63;
    const int wid  = tid >> 6;
    const int lr   = lane & 15;
    const int kg   = lane >> 4;

    const int bx   = blockIdx.x;                    // 0..1919
    const int fblk = (bx >> 3) & 1;
    const int mblk = ((bx >> 4) << 3) | (bx & 7);   // 0..959
    const long long rowBase = (long long)mblk * 64;

    // A-rebuild role: thread -> row wid*16+lr, k-slice kg
    const int arow = wid * 16 + lr;
    const long long am = rowBase + arow;
    const int ab = (int)(am / 15);
    const int at = (int)(am % 15);
    const unsigned char* atp = t0nib + (size_t)ab * 400 + kg * 4;  // + ks*16
    const int aWr = wid * 1024 + lane * 16;   // bytes into bufA[cur]

    // B: GLL source (lane 16B baked), dest wave-uniform
    const char* gB = (const char*)w1frag + (size_t)fblk * 409600
                   + (size_t)wid * 4096 + (size_t)lane * 16;       // + ks*16384

    f32x4 acc[4][4];
    #pragma unroll
    for (int i = 0; i < 4; ++i)
        #pragma unroll
        for (int j = 0; j < 4; ++j) acc[i][j] = {0.f, 0.f, 0.f, 0.f};

    // ---- prologue: stage ks=0 into buffer 0
    {
        #pragma unroll
        for (int i = 0; i < 4; ++i)
            GLL16(gB + i * 1024,
                  (lds_char_t*)smem + 8192 + (size_t)wid * 4096 + i * 1024);
        const unsigned int d = *(const unsigned int*)(atp);
        *(f16x8*)(smem + aWr) = rebuild_a(d, at);
    }
    __syncthreads();

    for (int ks = 0; ks < 25; ++ks) {
        const int cur = ks & 1;
        // ---- stage ks+1 into buffer cur^1 (issued before compute)
        if (ks + 1 < 25) {
            const char* src = gB + (size_t)(ks + 1) * 16384;
            lds_char_t* dst = (lds_char_t*)smem + 8192 + (size_t)(cur ^ 1) * 16384
                            + (size_t)wid * 4096;
            #pragma unroll
            for (int i = 0; i < 4; ++i)
                GLL16(src + i * 1024, dst + i * 1024);
            const unsigned int d = *(const unsigned int*)(atp + (ks + 1) * 16);
            *(f16x8*)(smem + (cur ^ 1) * 4096 + aWr) = rebuild_a(d, at);
        }
        // ---- compute from buffer cur
        const char* A = smem + cur * 4096;
        const char* B = smem + 8192 + cur * 16384 + wid * 4096;
        const f16x8 a0 = *(const f16x8*)(A + 0 * 1024 + lane * 16);
        const f16x8 a1 = *(const f16x8*)(A + 1 * 1024 + lane * 16);
        const f16x8 a2 = *(const f16x8*)(A + 2 * 1024 + lane * 16);
        const f16x8 a3 = *(const f16x8*)(A + 3 * 1024 + lane * 16);
        #pragma unroll
        for (int fn = 0; fn < 4; ++fn) {
            const f16x8 b = *(const f16x8*)(B + fn * 1024 + lane * 16);
            acc[0][fn] = __builtin_amdgcn_mfma_f32_16x16x32_f16(a0, b, acc[0][fn], 0, 0, 0);
            acc[1][fn] = __builtin_amdgcn_mfma_f32_16x16x32_f16(a1, b, acc[1][fn], 0, 0, 0);
            acc[2][fn] = __builtin_amdgcn_mfma_f32_16x16x32_f16(a2, b, acc[2][fn], 0, 0, 0);
            acc[3][fn] = __builtin_amdgcn_mfma_f32_16x16x32_f16(a3, b, acc[3][fn], 0, 0, 0);
        }
        __syncthreads();
    }

    // ---- epilogue: fixup + fire + coalesced writes
    #pragma unroll
    for (int fm = 0; fm < 4; ++fm) {
        #pragma unroll
        for (int fn = 0; fn < 4; ++fn) {
            const int f = fblk * 256 + wid * 64 + fn * 16 + lr;
            if (f < F1) {
                #pragma unroll
                for (int r = 0; r < 4; ++r) {
                    const long long m = rowBase + fm * 16 + kg * 4 + r;
                    float p = acc[fm][fn][r];
                    if (__builtin_expect(fabsf(p - CONV1_T) < FIX_DELTA, 0)) {
                        const long long bb = m / 15;
                        const int tt = (int)(m % 15);
                        p = fix_dot_t0(t0nib + (size_t)bb * 400,
                                       w1 + (size_t)f * KDIM, tt);
                    }
                    const bool fire = (p >= CONV1_T);
                    thr1[m * F1 + f] = fire ? p : 0.f;
                    spk1[m * F1 + f] = fire ? 1.f : 0.f;
                }
            }
        }
    }
}

// ------------------------------------------------------------------
// k_conv3: pot3[row,g] = sum_f spk1[row,f]*w3[g,f] via 16x16x32 f16 MFMA.
// One wave = 16 rows (R5-verified). A = spk1 (0/1, f16-exact);
// B[k=f][n=g] = w3[g,f] (f16, err <= 0.13 << 12.64 tolerance).
// ------------------------------------------------------------------
__global__ __launch_bounds__(256)
void k_conv3(const float* __restrict__ spk1, const float* __restrict__ w3,
             float* __restrict__ pot3)
{
    const int tid  = threadIdx.x;
    const int lane = tid & 63;
    const int wid  = tid >> 6;
    const int gw   = blockIdx.x * 4 + wid;    // 0..3839
    const long long row0 = (long long)gw * 16;
    const int lr = lane & 15;
    const int kg = lane >> 4;
    const int n  = (lr < 10) ? lr : 0;        // g (junk cols discarded)

    const float* arow = spk1 + (row0 + lr) * F1;
    const float* brow = w3 + (size_t)n * F1;

    f32x4 acc = {0.f, 0.f, 0.f, 0.f};
    #pragma unroll
    for (int ks = 0; ks < 16; ++ks) {
        const int k0 = ks * 32 + kg * 8;
        f16x8 a, b;
        if (k0 + 8 <= F1) {
            const f32x4 a0 = *(const f32x4*)(arow + k0);
            const f32x4 a1 = *(const f32x4*)(arow + k0 + 4);
            const f32x4 b0 = *(const f32x4*)(brow + k0);
            const f32x4 b1 = *(const f32x4*)(brow + k0 + 4);
            #pragma unroll
            for (int e = 0; e < 4; ++e) {
                a[e] = (_Float16)a0[e]; a[e + 4] = (_Float16)a1[e];
                b[e] = (_Float16)b0[e]; b[e + 4] = (_Float16)b1[e];
            }
        } else {
            #pragma unroll
            for (int e = 0; e < 8; ++e) {
                const int k = k0 + e;
                a[e] = (k < F1) ? (_Float16)arow[k] : (_Float16)0.f;
                b[e] = (k < F1) ? (_Float16)brow[k] : (_Float16)0.f;
            }
        }
        acc = __builtin_amdgcn_mfma_f32_16x16x32_f16(a, b, acc, 0, 0, 0);
    }
    if (lr < 10) {
        #pragma unroll
        for (int r = 0; r < 4; ++r) {
            const long long m = row0 + kg * 4 + r;
            pot3[m * 10 + lr] = acc[r];
        }
    }
}

// ------------------------------------------------------------------
// k_winner: winner-take-all per batch, faithful to reference algebra.
// ------------------------------------------------------------------
__global__ __launch_bounds__(256)
void k_winner(const float* __restrict__ pot3, float* __restrict__ outCls, int nB)
{
    const int b = blockIdx.x * 256 + threadIdx.x;
    if (b >= nB) return;
    const float* p = pot3 + (long long)b * 150 + 140;   // t = 14 row

    float pv[10], s[10];
    float mv = 0.f;
    #pragma unroll
    for (int g = 0; g < 10; ++g) {
        const float v = p[g];
        pv[g] = v;
        s[g]  = (v > 0.f) ? 1.f : ((v < 0.f) ? -1.f : 0.f);
        mv = fmaxf(mv, s[g] * v);
    }
    const float vbig = mv * 15.f;
    float bm = -INFINITY; int bi = 0;
    #pragma unroll
    for (int g = 0; g < 10; ++g) {
        const float tot = s[g] * pv[g] + s[g] * vbig;
        if (tot > bm) { bm = tot; bi = g; }
    }
    outCls[b] = (bm != 0.f) ? (float)bi : -1.f;
}

// ------------------------------------------------------------------
extern "C" void kernel_launch(void* const* d_in, const int* in_sizes, int n_in,
                              void* d_out, int out_size, void* d_ws, size_t ws_size,
                              hipStream_t stream)
{
    const float* inp = (const float*)d_in[0];
    const float* w1  = (const float*)d_in[1];
    const float* w3  = (const float*)d_in[2];

    float* out  = (float*)d_out;
    float* spk1 = out;
    float* thr1 = out + 30720000LL;
    float* pot3 = out + 61440000LL;
    float* cls  = out + 62054400LL;

    // Scratch: t0nib (1638400 B) + w1frag (819200 B) = 2457600 B.
    char* scratch = (ws_size >= 2457600) ? (char*)d_ws : (char*)pot3;
    unsigned int* t0nib  = (unsigned int*)scratch;
    _Float16*     w1frag = (_Float16*)(scratch + 1638400);

    k_t0    <<<1600, 256, 0, stream>>>(inp, t0nib);
    k_prep  <<<200,  256, 0, stream>>>(w1, w1frag);
    k_main  <<<1920, 256, 0, stream>>>(w1, (const unsigned char*)t0nib, w1frag,
                                       spk1, thr1);
    k_conv3 <<<960,  256, 0, stream>>>(spk1, w3, pot3);
    k_winner<<<16,   256, 0, stream>>>(pot3, cls, 4096);
}

// Round 9
// 273.859 us; speedup vs baseline: 1.2199x; 1.2199x over previous
//
#include <hip/hip_runtime.h>
#include <hip/hip_bf16.h>
#include <stdint.h>

// MozafariMNIST2018 forward. B=4096, T=15, HW=784, F1=500, F3=10.
// Output layout (float32, concatenated):
//   spk1 [4096*15*500] @ 0
//   thr1 [4096*15*500] @ 30720000
//   pot3 [4096*15*10]  @ 61440000
//   cls  [4096]        @ 62054400
//
// R9 = composition of proven-fast pieces:
//   k_prep  (R4): w1 -> single f16, GLL16-ready swizzled tiles (800KB)
//   k_conv1 (R3 structure): 128x256 tile, 8 waves, double-buffered LDS
//           (48KB -> 3 blocks/CU), 2-phase prefetch, ONE f16 MFMA per
//           (a-frag, b-frag) + near-threshold fp32 fixup (R4-proven).
//   k_conv3 (R5): MFMA over K=500, one wave = 16 rows (~15us).
//   k_winner: reference algebra.

typedef _Float16 f16x8 __attribute__((ext_vector_type(8)));
typedef float    f32x4 __attribute__((ext_vector_type(4)));

typedef __attribute__((address_space(3))) char        lds_char_t;
typedef const __attribute__((address_space(1))) char  gbl_char_t;

#define GLL16(gsrc, ldst) \
  __builtin_amdgcn_global_load_lds((gbl_char_t*)(gsrc), (lds_char_t*)(ldst), 16, 0, 0)

#define CONV1_T   26.3424f
#define FIX_DELTA 0.05f
#define KDIM 784
#define F1   500

// ------------------------------------------------------------------
// k_prep (R4): w1 [500x784] fp32 -> f16, in conv1's LDS tile byte order.
// Tile (nb*25+ks) is 16384 B; chunk c (16B): nl=c>>2 (row 0..255),
// slot=c&3, k-chunk j = slot ^ ((nl>>1)&3) (XOR bank swizzle).
// ------------------------------------------------------------------
__global__ __launch_bounds__(256)
void k_prep(const float* __restrict__ w1, float* __restrict__ scratch)
{
    const int c = blockIdx.x * 256 + threadIdx.x;   // < 51200
    const int tile  = c >> 10;
    const int chunk = c & 1023;
    const int nb   = tile / 25;
    const int ks   = tile % 25;
    const int nl   = chunk >> 2;
    const int slot = chunk & 3;
    const int j    = slot ^ ((nl >> 1) & 3);
    const int k0   = ks * 32 + j * 8;
    const int ng   = nb * 256 + nl;

    f16x8 v;
    #pragma unroll
    for (int e = 0; e < 8; ++e) {
        const int kk = k0 + e;
        v[e] = (ng < F1 && kk < KDIM) ? (_Float16)w1[ng * KDIM + kk] : (_Float16)0.f;
    }
    *(f16x8*)((char*)scratch + (size_t)c * 16) = v;
}

// exact fp32 recompute for near-threshold elements (rare; R4-proven)
__device__ __attribute__((noinline))
float fix_dot(const float* __restrict__ a, const float* __restrict__ w)
{
    float s0 = 0.f, s1 = 0.f, s2 = 0.f, s3 = 0.f;
    for (int k = 0; k < KDIM; k += 4) {
        s0 = fmaf(a[k],     w[k],     s0);
        s1 = fmaf(a[k + 1], w[k + 1], s1);
        s2 = fmaf(a[k + 2], w[k + 2], s2);
        s3 = fmaf(a[k + 3], w[k + 3], s3);
    }
    return (s0 + s1) + (s2 + s3);
}

// ------------------------------------------------------------------
// k_conv1: pot1 = A[61440x784] * w1^T (f16 + fixup), fused fire.
// Tile BM=128, BN=256 (nb half), BK=32. 512 thr = 8 waves (2M x 4N),
// per-wave 64x64 output. Double-buffered LDS (48KB), 2-phase prefetch.
// ------------------------------------------------------------------
__global__ __launch_bounds__(512, 4)
void k_conv1(const float* __restrict__ inp, const float* __restrict__ bsplit,
             const float* __restrict__ w1,
             float* __restrict__ spk1, float* __restrict__ thr1)
{
    __shared__ char smem[49152];
    _Float16* sA = (_Float16*)smem;              // 2 x 8192 B @ 0
    _Float16* sB = (_Float16*)(smem + 16384);    // 2 x 16384 B @ 16384

    const int tid  = threadIdx.x;
    const int lane = tid & 63;
    const int wid  = tid >> 6;     // 0..7
    const int wm   = wid >> 2;     // 0..1 (M)
    const int wn   = wid & 3;      // 0..3 (N)
    const int lr   = lane & 15;
    const int kg   = lane >> 4;

    // XCD pairing: bx and bx^8 share the same A tile on the same XCD.
    const int bx   = blockIdx.x;                    // 0..959
    const int nb   = (bx >> 3) & 1;
    const int mblk = ((bx >> 4) << 3) | (bx & 7);   // 0..479
    const long long rowBase = (long long)mblk * 128;

    // A staging role: thread -> (row sm, 8-wide k-chunk sk8)
    const int sm  = tid >> 2;      // 0..127
    const int sk8 = tid & 3;
    const int aWr = sm * 32 + (sk8 ^ ((sm >> 1) & 3)) * 8;
    const float* gA = inp + (rowBase + sm) * KDIM + sk8 * 8;

    // B: GLL16 source (lane's 16B baked in); 2 x 1KB per wave per stage
    const char* gBsrc = (const char*)bsplit + (size_t)(nb * 25) * 16384
                      + (size_t)wid * 2048 + (size_t)lane * 16;

    f32x4 acc[4][4];
    #pragma unroll
    for (int i = 0; i < 4; ++i)
        #pragma unroll
        for (int j = 0; j < 4; ++j) acc[i][j] = {0.f, 0.f, 0.f, 0.f};

    int aOff[4], bOff[4];
    #pragma unroll
    for (int fm = 0; fm < 4; ++fm) {
        const int r = wm * 64 + fm * 16 + lr;
        aOff[fm] = r * 32 + (kg ^ ((r >> 1) & 3)) * 8;
    }
    #pragma unroll
    for (int fn = 0; fn < 4; ++fn) {
        const int n = wn * 64 + fn * 16 + lr;
        bOff[fn] = n * 32 + (kg ^ ((n >> 1) & 3)) * 8;
    }

    // ---- prologue: stage ks=0 into buffer 0
    {
        const f32x4 x0 = *(const f32x4*)(gA);
        const f32x4 x1 = *(const f32x4*)(gA + 4);
        #pragma unroll
        for (int i = 0; i < 2; ++i)
            GLL16(gBsrc + i * 1024,
                  (lds_char_t*)smem + 16384 + (size_t)wid * 2048 + i * 1024);
        f16x8 v;
        #pragma unroll
        for (int e = 0; e < 4; ++e) { v[e] = (_Float16)x0[e]; v[e + 4] = (_Float16)x1[e]; }
        *(f16x8*)&sA[aWr] = v;
    }
    __syncthreads();

    for (int ks = 0; ks < 25; ++ks) {
        const int  cur = ks & 1;
        const bool pf  = (ks + 1 < 25);

        // ---- issue prefetch for tile ks+1 into buffer cur^1
        f32x4 x0 = {0.f, 0.f, 0.f, 0.f}, x1 = {0.f, 0.f, 0.f, 0.f};
        bool av = false;
        if (pf) {
            const int k0 = (ks + 1) * 32 + sk8 * 8;
            av = (k0 + 8 <= KDIM);
            if (av) {
                x0 = *(const f32x4*)(gA + (ks + 1) * 32);
                x1 = *(const f32x4*)(gA + (ks + 1) * 32 + 4);
            }
            const char*  src = gBsrc + (size_t)(ks + 1) * 16384;
            lds_char_t*  dst = (lds_char_t*)smem + 16384 + (size_t)(cur ^ 1) * 16384
                             + (size_t)wid * 2048;
            #pragma unroll
            for (int i = 0; i < 2; ++i)
                GLL16(src + i * 1024, dst + i * 1024);
        }

        // ---- compute tile ks from buffer cur
        const _Float16* sAc = sA + cur * 4096;
        const _Float16* sBc = sB + cur * 8192;
        const f16x8 a0 = *(const f16x8*)&sAc[aOff[0]];
        const f16x8 a1 = *(const f16x8*)&sAc[aOff[1]];
        const f16x8 a2 = *(const f16x8*)&sAc[aOff[2]];
        const f16x8 a3 = *(const f16x8*)&sAc[aOff[3]];
        #pragma unroll
        for (int fn = 0; fn < 4; ++fn) {
            const f16x8 b = *(const f16x8*)&sBc[bOff[fn]];
            acc[0][fn] = __builtin_amdgcn_mfma_f32_16x16x32_f16(a0, b, acc[0][fn], 0, 0, 0);
            acc[1][fn] = __builtin_amdgcn_mfma_f32_16x16x32_f16(a1, b, acc[1][fn], 0, 0, 0);
            acc[2][fn] = __builtin_amdgcn_mfma_f32_16x16x32_f16(a2, b, acc[2][fn], 0, 0, 0);
            acc[3][fn] = __builtin_amdgcn_mfma_f32_16x16x32_f16(a3, b, acc[3][fn], 0, 0, 0);
        }

        // ---- finish A prefetch: cvt + LDS write into buffer cur^1
        if (pf) {
            f16x8 v;
            #pragma unroll
            for (int e = 0; e < 4; ++e) {
                v[e]     = av ? (_Float16)x0[e] : (_Float16)0.f;
                v[e + 4] = av ? (_Float16)x1[e] : (_Float16)0.f;
            }
            *(f16x8*)&sA[(cur ^ 1) * 4096 + aWr] = v;
        }
        __syncthreads();
    }

    // ---- epilogue: fixup + fire. C/D: col=lane&15, row=(lane>>4)*4+r
    #pragma unroll
    for (int fm = 0; fm < 4; ++fm) {
        #pragma unroll
        for (int fn = 0; fn < 4; ++fn) {
            const int ng = nb * 256 + wn * 64 + fn * 16 + lr;
            if (ng < F1) {
                #pragma unroll
                for (int r = 0; r < 4; ++r) {
                    const long long m = rowBase + wm * 64 + fm * 16 + kg * 4 + r;
                    float p = acc[fm][fn][r];
                    if (__builtin_expect(fabsf(p - CONV1_T) < FIX_DELTA, 0))
                        p = fix_dot(inp + m * KDIM, w1 + (size_t)ng * KDIM);
                    const bool fire = (p >= CONV1_T);
                    thr1[m * F1 + ng] = fire ? p : 0.f;
                    spk1[m * F1 + ng] = fire ? 1.f : 0.f;
                }
            }
        }
    }
}

// ------------------------------------------------------------------
// k_conv3 (R5-verified): pot3[row,g] = sum_f spk1[row,f]*w3[g,f] via
// 16x16x32 f16 MFMA. One wave = 16 rows. A = spk1 (0/1, f16-exact);
// B[k=f][n=g] = w3[g,f] (f16, err <= 0.13 << 12.64 tolerance).
// ------------------------------------------------------------------
__global__ __launch_bounds__(256)
void k_conv3(const float* __restrict__ spk1, const float* __restrict__ w3,
             float* __restrict__ pot3)
{
    const int tid  = threadIdx.x;
    const int lane = tid & 63;
    const int wid  = tid >> 6;
    const int gw   = blockIdx.x * 4 + wid;    // 0..3839
    const long long row0 = (long long)gw * 16;
    const int lr = lane & 15;
    const int kg = lane >> 4;
    const int n  = (lr < 10) ? lr : 0;        // g (junk cols discarded)

    const float* arow = spk1 + (row0 + lr) * F1;
    const float* brow = w3 + (size_t)n * F1;

    f32x4 acc = {0.f, 0.f, 0.f, 0.f};
    #pragma unroll
    for (int ks = 0; ks < 16; ++ks) {
        const int k0 = ks * 32 + kg * 8;
        f16x8 a, b;
        if (k0 + 8 <= F1) {
            const f32x4 a0 = *(const f32x4*)(arow + k0);
            const f32x4 a1 = *(const f32x4*)(arow + k0 + 4);
            const f32x4 b0 = *(const f32x4*)(brow + k0);
            const f32x4 b1 = *(const f32x4*)(brow + k0 + 4);
            #pragma unroll
            for (int e = 0; e < 4; ++e) {
                a[e] = (_Float16)a0[e]; a[e + 4] = (_Float16)a1[e];
                b[e] = (_Float16)b0[e]; b[e + 4] = (_Float16)b1[e];
            }
        } else {
            #pragma unroll
            for (int e = 0; e < 8; ++e) {
                const int k = k0 + e;
                a[e] = (k < F1) ? (_Float16)arow[k] : (_Float16)0.f;
                b[e] = (k < F1) ? (_Float16)brow[k] : (_Float16)0.f;
            }
        }
        acc = __builtin_amdgcn_mfma_f32_16x16x32_f16(a, b, acc, 0, 0, 0);
    }
    if (lr < 10) {
        #pragma unroll
        for (int r = 0; r < 4; ++r) {
            const long long m = row0 + kg * 4 + r;
            pot3[m * 10 + lr] = acc[r];
        }
    }
}

// ------------------------------------------------------------------
// k_winner: winner-take-all per batch, faithful to reference algebra.
// ------------------------------------------------------------------
__global__ __launch_bounds__(256)
void k_winner(const float* __restrict__ pot3, float* __restrict__ outCls, int nB)
{
    const int b = blockIdx.x * 256 + threadIdx.x;
    if (b >= nB) return;
    const float* p = pot3 + (long long)b * 150 + 140;   // t = 14 row

    float pv[10], s[10];
    float mv = 0.f;
    #pragma unroll
    for (int g = 0; g < 10; ++g) {
        const float v = p[g];
        pv[g] = v;
        s[g]  = (v > 0.f) ? 1.f : ((v < 0.f) ? -1.f : 0.f);
        mv = fmaxf(mv, s[g] * v);
    }
    const float vbig = mv * 15.f;
    float bm = -INFINITY; int bi = 0;
    #pragma unroll
    for (int g = 0; g < 10; ++g) {
        const float tot = s[g] * pv[g] + s[g] * vbig;
        if (tot > bm) { bm = tot; bi = g; }
    }
    outCls[b] = (bm != 0.f) ? (float)bi : -1.f;
}

// ------------------------------------------------------------------
extern "C" void kernel_launch(void* const* d_in, const int* in_sizes, int n_in,
                              void* d_out, int out_size, void* d_ws, size_t ws_size,
                              hipStream_t stream)
{
    const float* inp = (const float*)d_in[0];
    const float* w1  = (const float*)d_in[1];
    const float* w3  = (const float*)d_in[2];

    float* out  = (float*)d_out;
    float* spk1 = out;
    float* thr1 = out + 30720000LL;
    float* pot3 = out + 61440000LL;
    float* cls  = out + 62054400LL;

    // Weight scratch: 819200 B. Prefer d_ws; else borrow the pot3 region
    // (read-only in conv1; conv3 overwrites it afterwards).
    float* scratch = (ws_size >= 819200) ? (float*)d_ws : pot3;

    k_prep  <<<200, 256, 0, stream>>>(w1, scratch);
    k_conv1 <<<960, 512, 0, stream>>>(inp, scratch, w1, spk1, thr1);
    k_conv3 <<<960, 256, 0, stream>>>(spk1, w3, pot3);
    k_winner<<<16,  256, 0, stream>>>(pot3, cls, 4096);
}

// Round 10
// 270.574 us; speedup vs baseline: 1.2348x; 1.0121x over previous
//
#include <hip/hip_runtime.h>
#include <hip/hip_bf16.h>
#include <stdint.h>

// MozafariMNIST2018 forward. B=4096, T=15, HW=784, F1=500, F3=10.
// Output layout (float32, concatenated):
//   spk1 [4096*15*500] @ 0
//   thr1 [4096*15*500] @ 30720000
//   pot3 [4096*15*10]  @ 61440000
//   cls  [4096]        @ 62054400
//
// R10: R9's single-f16 conv1, upgraded 2-buf -> 3-buf LDS pipeline with
// COUNTED vmcnt (T3/T4): iter k stages (k+2), computes k, finishes A(k+1),
// waits vmcnt(4) (never 0) + one barrier. B GLL16s get ~2 compute phases
// of latency cover, A register-loads ~1.5. LDS 72KB -> 2 blocks/CU.
// conv3 = R5-verified MFMA kernel. Near-threshold fp32 fixup keeps spikes
// exact (R4-proven).

typedef _Float16 f16x8 __attribute__((ext_vector_type(8)));
typedef float    f32x4 __attribute__((ext_vector_type(4)));

typedef __attribute__((address_space(3))) char        lds_char_t;
typedef const __attribute__((address_space(1))) char  gbl_char_t;

#define GLL16(gsrc, ldst) \
  __builtin_amdgcn_global_load_lds((gbl_char_t*)(gsrc), (lds_char_t*)(ldst), 16, 0, 0)

#define CONV1_T   26.3424f
#define FIX_DELTA 0.05f
#define KDIM 784
#define F1   500

// ------------------------------------------------------------------
// k_prep (R4/R9): w1 [500x784] fp32 -> f16, conv1 LDS tile byte order.
// Tile (nb*25+ks) is 16384 B; chunk c (16B): nl=c>>2 (row), slot=c&3,
// k-chunk j = slot ^ ((nl>>1)&3) (XOR bank swizzle).
// ------------------------------------------------------------------
__global__ __launch_bounds__(256)
void k_prep(const float* __restrict__ w1, float* __restrict__ scratch)
{
    const int c = blockIdx.x * 256 + threadIdx.x;   // < 51200
    const int tile  = c >> 10;
    const int chunk = c & 1023;
    const int nb   = tile / 25;
    const int ks   = tile % 25;
    const int nl   = chunk >> 2;
    const int slot = chunk & 3;
    const int j    = slot ^ ((nl >> 1) & 3);
    const int k0   = ks * 32 + j * 8;
    const int ng   = nb * 256 + nl;

    f16x8 v;
    #pragma unroll
    for (int e = 0; e < 8; ++e) {
        const int kk = k0 + e;
        v[e] = (ng < F1 && kk < KDIM) ? (_Float16)w1[ng * KDIM + kk] : (_Float16)0.f;
    }
    *(f16x8*)((char*)scratch + (size_t)c * 16) = v;
}

// exact fp32 recompute for near-threshold elements (rare; R4-proven)
__device__ __attribute__((noinline))
float fix_dot(const float* __restrict__ a, const float* __restrict__ w)
{
    float s0 = 0.f, s1 = 0.f, s2 = 0.f, s3 = 0.f;
    for (int k = 0; k < KDIM; k += 4) {
        s0 = fmaf(a[k],     w[k],     s0);
        s1 = fmaf(a[k + 1], w[k + 1], s1);
        s2 = fmaf(a[k + 2], w[k + 2], s2);
        s3 = fmaf(a[k + 3], w[k + 3], s3);
    }
    return (s0 + s1) + (s2 + s3);
}

// ------------------------------------------------------------------
// k_conv1: pot1 = A[61440x784] * w1^T (f16 + fixup), fused fire.
// Tile BM=128, BN=256 (nb half), BK=32. 512 thr = 8 waves (2M x 4N).
// 3-buffer LDS (sA 3x8KB @0, sB 3x16KB @24576), counted-vmcnt pipeline.
// ------------------------------------------------------------------
__global__ __launch_bounds__(512, 4)
void k_conv1(const float* __restrict__ inp, const float* __restrict__ bsplit,
             const float* __restrict__ w1,
             float* __restrict__ spk1, float* __restrict__ thr1)
{
    __shared__ char smem[73728];

    const int tid  = threadIdx.x;
    const int lane = tid & 63;
    const int wid  = tid >> 6;     // 0..7
    const int wm   = wid >> 2;     // 0..1 (M)
    const int wn   = wid & 3;      // 0..3 (N)
    const int lr   = lane & 15;
    const int kg   = lane >> 4;

    // XCD pairing: bx and bx^8 share the same A tile on the same XCD.
    const int bx   = blockIdx.x;                    // 0..959
    const int nb   = (bx >> 3) & 1;
    const int mblk = ((bx >> 4) << 3) | (bx & 7);   // 0..479
    const long long rowBase = (long long)mblk * 128;

    // A staging role: thread -> (row sm, 8-wide k-chunk sk8)
    const int sm  = tid >> 2;      // 0..127
    const int sk8 = tid & 3;
    const int aWr = (sm * 32 + (sk8 ^ ((sm >> 1) & 3)) * 8) * 2;   // bytes
    const float* gA = inp + (rowBase + sm) * KDIM + sk8 * 8;

    // B: GLL16 source (lane's 16B baked in); 2 x 1KB per wave per stage
    const char* gBsrc = (const char*)bsplit + (size_t)(nb * 25) * 16384
                      + (size_t)wid * 2048 + (size_t)lane * 16;
    const int bDstOff = wid * 2048;     // within a sB buffer

    f32x4 acc[4][4];
    #pragma unroll
    for (int i = 0; i < 4; ++i)
        #pragma unroll
        for (int j = 0; j < 4; ++j) acc[i][j] = {0.f, 0.f, 0.f, 0.f};

    int aOff[4], bOff[4];   // half-units within a buffer
    #pragma unroll
    for (int fm = 0; fm < 4; ++fm) {
        const int r = wm * 64 + fm * 16 + lr;
        aOff[fm] = r * 32 + (kg ^ ((r >> 1) & 3)) * 8;
    }
    #pragma unroll
    for (int fn = 0; fn < 4; ++fn) {
        const int n = wn * 64 + fn * 16 + lr;
        bOff[fn] = n * 32 + (kg ^ ((n >> 1) & 3)) * 8;
    }

    // A-load helper values
    f32x4 rA0 = {0.f,0.f,0.f,0.f}, rA1 = {0.f,0.f,0.f,0.f};  // step k+1 regs
    bool  av1 = false;

    // ---- prologue ----
    // stage B(0) -> buf0; A(0): load, cvt, write bufA0
    #pragma unroll
    for (int i = 0; i < 2; ++i)
        GLL16(gBsrc + i * 1024, (lds_char_t*)smem + 24576 + bDstOff + i * 1024);
    {
        const f32x4 x0 = *(const f32x4*)(gA);
        const f32x4 x1 = *(const f32x4*)(gA + 4);
        f16x8 v;
        #pragma unroll
        for (int e = 0; e < 4; ++e) { v[e] = (_Float16)x0[e]; v[e + 4] = (_Float16)x1[e]; }
        *(f16x8*)(smem + aWr) = v;
    }
    // stage B(1) -> buf1; load A(1) into regs (held)
    #pragma unroll
    for (int i = 0; i < 2; ++i)
        GLL16(gBsrc + 16384 + i * 1024,
              (lds_char_t*)smem + 24576 + 16384 + bDstOff + i * 1024);
    {
        const int k0 = 32 + sk8 * 8;
        av1 = (k0 + 8 <= KDIM);
        rA0 = *(const f32x4*)(gA + 32);
        rA1 = *(const f32x4*)(gA + 32 + 4);
    }
    asm volatile("s_waitcnt vmcnt(4)" ::: "memory");   // B(0) done; B(1)/A(1) in flight
    __syncthreads();

    for (int ks = 0; ks < 25; ++ks) {
        const int c0 = ks % 3;
        const int c1 = (ks + 1) % 3;
        const int c2 = (ks + 2) % 3;

        // ---- issue stage for ks+2: B via GLL16, A into regs
        f32x4 nA0 = {0.f,0.f,0.f,0.f}, nA1 = {0.f,0.f,0.f,0.f};
        bool  av2 = false;
        if (ks + 2 < 25) {
            const char* src = gBsrc + (size_t)(ks + 2) * 16384;
            lds_char_t* dst = (lds_char_t*)smem + 24576 + (size_t)c2 * 16384 + bDstOff;
            #pragma unroll
            for (int i = 0; i < 2; ++i)
                GLL16(src + i * 1024, dst + i * 1024);
            const int k0 = (ks + 2) * 32 + sk8 * 8;
            av2 = (k0 + 8 <= KDIM);
            if (av2) {
                nA0 = *(const f32x4*)(gA + (ks + 2) * 32);
                nA1 = *(const f32x4*)(gA + (ks + 2) * 32 + 4);
            }
        }

        // ---- compute tile ks from buffer c0
        const _Float16* sAc = (const _Float16*)(smem + (size_t)c0 * 8192);
        const _Float16* sBc = (const _Float16*)(smem + 24576 + (size_t)c0 * 16384);
        const f16x8 a0 = *(const f16x8*)&sAc[aOff[0]];
        const f16x8 a1 = *(const f16x8*)&sAc[aOff[1]];
        const f16x8 a2 = *(const f16x8*)&sAc[aOff[2]];
        const f16x8 a3 = *(const f16x8*)&sAc[aOff[3]];
        #pragma unroll
        for (int fn = 0; fn < 4; ++fn) {
            const f16x8 b = *(const f16x8*)&sBc[bOff[fn]];
            acc[0][fn] = __builtin_amdgcn_mfma_f32_16x16x32_f16(a0, b, acc[0][fn], 0, 0, 0);
            acc[1][fn] = __builtin_amdgcn_mfma_f32_16x16x32_f16(a1, b, acc[1][fn], 0, 0, 0);
            acc[2][fn] = __builtin_amdgcn_mfma_f32_16x16x32_f16(a2, b, acc[2][fn], 0, 0, 0);
            acc[3][fn] = __builtin_amdgcn_mfma_f32_16x16x32_f16(a3, b, acc[3][fn], 0, 0, 0);
        }

        // ---- finish A(ks+1): cvt + ds_write into bufA c1 (compiler waits
        // on rA0/rA1; those were issued AFTER B(ks+1)'s GLL16s, so that
        // wait also retires B(ks+1))
        if (ks + 1 < 25) {
            f16x8 v;
            #pragma unroll
            for (int e = 0; e < 4; ++e) {
                v[e]     = av1 ? (_Float16)rA0[e] : (_Float16)0.f;
                v[e + 4] = av1 ? (_Float16)rA1[e] : (_Float16)0.f;
            }
            *(f16x8*)(smem + (size_t)c1 * 8192 + aWr) = v;
        }
        rA0 = nA0; rA1 = nA1; av1 = av2;

        // ---- counted drain (never 0): ks+2 loads stay in flight
        asm volatile("s_waitcnt vmcnt(4)" ::: "memory");
        __syncthreads();
    }

    // ---- epilogue: fixup + fire. C/D: col=lane&15, row=(lane>>4)*4+r
    #pragma unroll
    for (int fm = 0; fm < 4; ++fm) {
        #pragma unroll
        for (int fn = 0; fn < 4; ++fn) {
            const int ng = nb * 256 + wn * 64 + fn * 16 + lr;
            if (ng < F1) {
                #pragma unroll
                for (int r = 0; r < 4; ++r) {
                    const long long m = rowBase + wm * 64 + fm * 16 + kg * 4 + r;
                    float p = acc[fm][fn][r];
                    if (__builtin_expect(fabsf(p - CONV1_T) < FIX_DELTA, 0))
                        p = fix_dot(inp + m * KDIM, w1 + (size_t)ng * KDIM);
                    const bool fire = (p >= CONV1_T);
                    thr1[m * F1 + ng] = fire ? p : 0.f;
                    spk1[m * F1 + ng] = fire ? 1.f : 0.f;
                }
            }
        }
    }
}

// ------------------------------------------------------------------
// k_conv3 (R5-verified): pot3[row,g] = sum_f spk1[row,f]*w3[g,f] via
// 16x16x32 f16 MFMA. One wave = 16 rows. A = spk1 (0/1, f16-exact);
// B[k=f][n=g] = w3[g,f] (f16, err <= 0.13 << 12.64 tolerance).
// ------------------------------------------------------------------
__global__ __launch_bounds__(256)
void k_conv3(const float* __restrict__ spk1, const float* __restrict__ w3,
             float* __restrict__ pot3)
{
    const int tid  = threadIdx.x;
    const int lane = tid & 63;
    const int wid  = tid >> 6;
    const int gw   = blockIdx.x * 4 + wid;    // 0..3839
    const long long row0 = (long long)gw * 16;
    const int lr = lane & 15;
    const int kg = lane >> 4;
    const int n  = (lr < 10) ? lr : 0;        // g (junk cols discarded)

    const float* arow = spk1 + (row0 + lr) * F1;
    const float* brow = w3 + (size_t)n * F1;

    f32x4 acc = {0.f, 0.f, 0.f, 0.f};
    #pragma unroll
    for (int ks = 0; ks < 16; ++ks) {
        const int k0 = ks * 32 + kg * 8;
        f16x8 a, b;
        if (k0 + 8 <= F1) {
            const f32x4 a0 = *(const f32x4*)(arow + k0);
            const f32x4 a1 = *(const f32x4*)(arow + k0 + 4);
            const f32x4 b0 = *(const f32x4*)(brow + k0);
            const f32x4 b1 = *(const f32x4*)(brow + k0 + 4);
            #pragma unroll
            for (int e = 0; e < 4; ++e) {
                a[e] = (_Float16)a0[e]; a[e + 4] = (_Float16)a1[e];
                b[e] = (_Float16)b0[e]; b[e + 4] = (_Float16)b1[e];
            }
        } else {
            #pragma unroll
            for (int e = 0; e < 8; ++e) {
                const int k = k0 + e;
                a[e] = (k < F1) ? (_Float16)arow[k] : (_Float16)0.f;
                b[e] = (k < F1) ? (_Float16)brow[k] : (_Float16)0.f;
            }
        }
        acc = __builtin_amdgcn_mfma_f32_16x16x32_f16(a, b, acc, 0, 0, 0);
    }
    if (lr < 10) {
        #pragma unroll
        for (int r = 0; r < 4; ++r) {
            const long long m = row0 + kg * 4 + r;
            pot3[m * 10 + lr] = acc[r];
        }
    }
}

// ------------------------------------------------------------------
// k_winner: winner-take-all per batch, faithful to reference algebra.
// ------------------------------------------------------------------
__global__ __launch_bounds__(256)
void k_winner(const float* __restrict__ pot3, float* __restrict__ outCls, int nB)
{
    const int b = blockIdx.x * 256 + threadIdx.x;
    if (b >= nB) return;
    const float* p = pot3 + (long long)b * 150 + 140;   // t = 14 row

    float pv[10], s[10];
    float mv = 0.f;
    #pragma unroll
    for (int g = 0; g < 10; ++g) {
        const float v = p[g];
        pv[g] = v;
        s[g]  = (v > 0.f) ? 1.f : ((v < 0.f) ? -1.f : 0.f);
        mv = fmaxf(mv, s[g] * v);
    }
    const float vbig = mv * 15.f;
    float bm = -INFINITY; int bi = 0;
    #pragma unroll
    for (int g = 0; g < 10; ++g) {
        const float tot = s[g] * pv[g] + s[g] * vbig;
        if (tot > bm) { bm = tot; bi = g; }
    }
    outCls[b] = (bm != 0.f) ? (float)bi : -1.f;
}

// ------------------------------------------------------------------
extern "C" void kernel_launch(void* const* d_in, const int* in_sizes, int n_in,
                              void* d_out, int out_size, void* d_ws, size_t ws_size,
                              hipStream_t stream)
{
    const float* inp = (const float*)d_in[0];
    const float* w1  = (const float*)d_in[1];
    const float* w3  = (const float*)d_in[2];

    float* out  = (float*)d_out;
    float* spk1 = out;
    float* thr1 = out + 30720000LL;
    float* pot3 = out + 61440000LL;
    float* cls  = out + 62054400LL;

    // Weight scratch: 819200 B. Prefer d_ws; else borrow the pot3 region
    // (read-only in conv1; conv3 overwrites it afterwards).
    float* scratch = (ws_size >= 819200) ? (float*)d_ws : pot3;

    k_prep  <<<200, 256, 0, stream>>>(w1, scratch);
    k_conv1 <<<960, 512, 0, stream>>>(inp, scratch, w1, spk1, thr1);
    k_conv3 <<<960, 256, 0, stream>>>(spk1, w3, pot3);
    k_winner<<<16,  256, 0, stream>>>(pot3, cls, 4096);
}

// Round 11
// 205.204 us; speedup vs baseline: 1.6281x; 1.3186x over previous
//
#include <hip/hip_runtime.h>
#include <hip/hip_bf16.h>
#include <stdint.h>

// MozafariMNIST2018 forward. B=4096, T=15, HW=784, F1=500, F3=10.
// Output layout (float32, concatenated):
//   spk1 [4096*15*500] @ 0
//   thr1 [4096*15*500] @ 30720000
//   pot3 [4096*15*10]  @ 61440000
//   cls  [4096]        @ 62054400
//
// R11 = best measured pieces, composed:
//   k_prep + k_conv1: R3 verbatim (hi/lo split-f16 MFMA pairs -> exact
//     spikes without fixup; 128x256 tile, 8 waves, 80KB dbuf LDS, GLL16
//     B-staging, 2-phase prefetch). Measured 187us @ R3.
//   k_conv3: R5 verbatim (16x16x32 f16 MFMA over K=500, one wave = 16
//     rows). Measured ~15us @ R5/R9.
//   k_winner: reference algebra.

typedef _Float16 f16x8 __attribute__((ext_vector_type(8)));
typedef float    f32x4 __attribute__((ext_vector_type(4)));

typedef __attribute__((address_space(3))) char        lds_char_t;
typedef const __attribute__((address_space(1))) char  gbl_char_t;

#define GLL16(gsrc, ldst) \
  __builtin_amdgcn_global_load_lds((gbl_char_t*)(gsrc), (lds_char_t*)(ldst), 16, 0, 0)

#define CONV1_T 26.3424f
#define KDIM 784
#define F1   500

// ------------------------------------------------------------------
// k_prep (R3): split w1 [500x784] fp32 into f16 hi/lo, laid out exactly
// as the conv1 LDS tile bytes so conv1 can global_load_lds it linearly.
// Tile (nb*25+ks) is 32768 B: byte b -> part=b>>14 (0=hi,1=lo),
// nl=(b&16383)>>6, slot=(b>>4)&3, e=(b>>1)&7, k-chunk j = slot^((nl>>1)&3).
// ------------------------------------------------------------------
__global__ __launch_bounds__(256)
void k_prep(const float* __restrict__ w1, float* __restrict__ scratch)
{
    const int c = blockIdx.x * 256 + threadIdx.x;   // one 16B chunk each
    const int tile  = c >> 11;
    const int chunk = c & 2047;
    const int nb   = tile / 25;
    const int ks   = tile % 25;
    const int part = chunk >> 10;
    const int nl   = (chunk & 1023) >> 2;
    const int slot = chunk & 3;
    const int j    = slot ^ ((nl >> 1) & 3);
    const int k0   = ks * 32 + j * 8;
    const int ng   = nb * 256 + nl;

    f16x8 v;
    #pragma unroll
    for (int e = 0; e < 8; ++e) {
        const int kk = k0 + e;
        const float val = (ng < F1 && kk < KDIM) ? w1[ng * KDIM + kk] : 0.f;
        const _Float16 h = (_Float16)val;
        v[e] = part ? (_Float16)(val - (float)h) : h;
    }
    *(f16x8*)((char*)scratch + (size_t)c * 16) = v;
}

// ------------------------------------------------------------------
// k_conv1 (R3): pot1 = A[61440x784] * w1^T, split-f16 MFMA, fused fire.
// Tile BM=128, BN=256 (nb half), BK=32. 512 threads = 8 waves (2M x 4N),
// per-wave 64x64 output. Double-buffered LDS + 2-phase prefetch.
// ------------------------------------------------------------------
__global__ __launch_bounds__(512, 4)
void k_conv1(const float* __restrict__ inp, const float* __restrict__ bsplit,
             float* __restrict__ spk1, float* __restrict__ thr1)
{
    __shared__ _Float16 sA[2][128 * 32];        // 2 x 8 KB
    __shared__ _Float16 sB[2][2 * 256 * 32];    // 2 x 32 KB (hi @0, lo @8192 halfs)

    const int tid  = threadIdx.x;
    const int lane = tid & 63;
    const int wid  = tid >> 6;     // 0..7
    const int wm   = wid >> 2;     // 0..1 (M)
    const int wn   = wid & 3;      // 0..3 (N)
    const int lr   = lane & 15;
    const int kg   = lane >> 4;

    // XCD pairing: bx and bx+8 share the same A tile on the same XCD.
    const int bx   = blockIdx.x;                    // 0..959
    const int nb   = (bx >> 3) & 1;
    const int mblk = ((bx >> 4) << 3) | (bx & 7);   // 0..479
    const long long rowBase = (long long)mblk * 128;

    // A staging role: thread -> (row sm, 8-wide k-chunk sk8)
    const int sm  = tid >> 2;      // 0..127
    const int sk8 = tid & 3;
    const int aWr = sm * 32 + (sk8 ^ ((sm >> 1) & 3)) * 8;
    const float* gA = inp + (rowBase + sm) * KDIM + sk8 * 8;

    // B: global_load_lds source (lane's 16B baked in); 4 x 1KB issues per wave
    const char* gBsrc = (const char*)bsplit + (size_t)(nb * 25) * 32768
                      + (size_t)wid * 4096 + (size_t)lane * 16;

    f32x4 acc[4][4];
    #pragma unroll
    for (int i = 0; i < 4; ++i)
        #pragma unroll
        for (int j = 0; j < 4; ++j) acc[i][j] = {0.f, 0.f, 0.f, 0.f};

    int aOff[4], bOff[4];
    #pragma unroll
    for (int fm = 0; fm < 4; ++fm) {
        const int r = wm * 64 + fm * 16 + lr;
        aOff[fm] = r * 32 + (kg ^ ((r >> 1) & 3)) * 8;
    }
    #pragma unroll
    for (int fn = 0; fn < 4; ++fn) {
        const int n = wn * 64 + fn * 16 + lr;
        bOff[fn] = n * 32 + (kg ^ ((n >> 1) & 3)) * 8;
    }

    // ---- prologue: stage ks=0 into buffer 0
    {
        const f32x4 x0 = *(const f32x4*)(gA);
        const f32x4 x1 = *(const f32x4*)(gA + 4);
        #pragma unroll
        for (int i = 0; i < 4; ++i)
            GLL16(gBsrc + i * 1024, (lds_char_t*)&sB[0][0] + wid * 4096 + i * 1024);
        f16x8 v;
        #pragma unroll
        for (int e = 0; e < 4; ++e) { v[e] = (_Float16)x0[e]; v[e + 4] = (_Float16)x1[e]; }
        *(f16x8*)&sA[0][aWr] = v;
    }
    __syncthreads();

    for (int ks = 0; ks < 25; ++ks) {
        const int  cur = ks & 1;
        const bool pf  = (ks + 1 < 25);

        // ---- issue prefetch for tile ks+1 into buffer cur^1
        f32x4 x0 = {0.f, 0.f, 0.f, 0.f}, x1 = {0.f, 0.f, 0.f, 0.f};
        bool av = false;
        if (pf) {
            const int k0 = (ks + 1) * 32 + sk8 * 8;
            av = (k0 + 8 <= KDIM);
            if (av) {
                x0 = *(const f32x4*)(gA + (ks + 1) * 32);
                x1 = *(const f32x4*)(gA + (ks + 1) * 32 + 4);
            }
            const char*  src = gBsrc + (size_t)(ks + 1) * 32768;
            lds_char_t*  dst = (lds_char_t*)&sB[cur ^ 1][0] + wid * 4096;
            #pragma unroll
            for (int i = 0; i < 4; ++i)
                GLL16(src + i * 1024, dst + i * 1024);
        }

        // ---- compute tile ks from buffer cur
        const f16x8 a0 = *(const f16x8*)&sA[cur][aOff[0]];
        const f16x8 a1 = *(const f16x8*)&sA[cur][aOff[1]];
        const f16x8 a2 = *(const f16x8*)&sA[cur][aOff[2]];
        const f16x8 a3 = *(const f16x8*)&sA[cur][aOff[3]];
        #pragma unroll
        for (int fn = 0; fn < 4; ++fn) {
            const f16x8 bh = *(const f16x8*)&sB[cur][bOff[fn]];
            const f16x8 bl = *(const f16x8*)&sB[cur][8192 + bOff[fn]];
            acc[0][fn] = __builtin_amdgcn_mfma_f32_16x16x32_f16(a0, bh, acc[0][fn], 0, 0, 0);
            acc[0][fn] = __builtin_amdgcn_mfma_f32_16x16x32_f16(a0, bl, acc[0][fn], 0, 0, 0);
            acc[1][fn] = __builtin_amdgcn_mfma_f32_16x16x32_f16(a1, bh, acc[1][fn], 0, 0, 0);
            acc[1][fn] = __builtin_amdgcn_mfma_f32_16x16x32_f16(a1, bl, acc[1][fn], 0, 0, 0);
            acc[2][fn] = __builtin_amdgcn_mfma_f32_16x16x32_f16(a2, bh, acc[2][fn], 0, 0, 0);
            acc[2][fn] = __builtin_amdgcn_mfma_f32_16x16x32_f16(a2, bl, acc[2][fn], 0, 0, 0);
            acc[3][fn] = __builtin_amdgcn_mfma_f32_16x16x32_f16(a3, bh, acc[3][fn], 0, 0, 0);
            acc[3][fn] = __builtin_amdgcn_mfma_f32_16x16x32_f16(a3, bl, acc[3][fn], 0, 0, 0);
        }

        // ---- finish A prefetch: cvt + LDS write into buffer cur^1
        if (pf) {
            f16x8 v;
            #pragma unroll
            for (int e = 0; e < 4; ++e) {
                v[e]     = av ? (_Float16)x0[e] : (_Float16)0.f;
                v[e + 4] = av ? (_Float16)x1[e] : (_Float16)0.f;
            }
            *(f16x8*)&sA[cur ^ 1][aWr] = v;
        }
        __syncthreads();
    }

    // ---- epilogue: fire. C/D layout: col = lane&15, row = (lane>>4)*4 + r
    #pragma unroll
    for (int fm = 0; fm < 4; ++fm) {
        #pragma unroll
        for (int fn = 0; fn < 4; ++fn) {
            const int ng = nb * 256 + wn * 64 + fn * 16 + lr;
            if (ng < F1) {
                #pragma unroll
                for (int r = 0; r < 4; ++r) {
                    const long long m = rowBase + wm * 64 + fm * 16 + kg * 4 + r;
                    const float p   = acc[fm][fn][r];
                    const bool fire = (p >= CONV1_T);
                    thr1[m * F1 + ng] = fire ? p : 0.f;
                    spk1[m * F1 + ng] = fire ? 1.f : 0.f;
                }
            }
        }
    }
}

// ------------------------------------------------------------------
// k_conv3 (R5-verified): pot3[row,g] = sum_f spk1[row,f]*w3[g,f] via
// 16x16x32 f16 MFMA. One wave = 16 rows. A = spk1 (0/1, f16-exact);
// B[k=f][n=g] = w3[g,f] (f16, err <= 0.13 << 12.64 tolerance).
// ------------------------------------------------------------------
__global__ __launch_bounds__(256)
void k_conv3(const float* __restrict__ spk1, const float* __restrict__ w3,
             float* __restrict__ pot3)
{
    const int tid  = threadIdx.x;
    const int lane = tid & 63;
    const int wid  = tid >> 6;
    const int gw   = blockIdx.x * 4 + wid;    // 0..3839
    const long long row0 = (long long)gw * 16;
    const int lr = lane & 15;
    const int kg = lane >> 4;
    const int n  = (lr < 10) ? lr : 0;        // g (junk cols discarded)

    const float* arow = spk1 + (row0 + lr) * F1;
    const float* brow = w3 + (size_t)n * F1;

    f32x4 acc = {0.f, 0.f, 0.f, 0.f};
    #pragma unroll
    for (int ks = 0; ks < 16; ++ks) {
        const int k0 = ks * 32 + kg * 8;
        f16x8 a, b;
        if (k0 + 8 <= F1) {
            const f32x4 a0 = *(const f32x4*)(arow + k0);
            const f32x4 a1 = *(const f32x4*)(arow + k0 + 4);
            const f32x4 b0 = *(const f32x4*)(brow + k0);
            const f32x4 b1 = *(const f32x4*)(brow + k0 + 4);
            #pragma unroll
            for (int e = 0; e < 4; ++e) {
                a[e] = (_Float16)a0[e]; a[e + 4] = (_Float16)a1[e];
                b[e] = (_Float16)b0[e]; b[e + 4] = (_Float16)b1[e];
            }
        } else {
            #pragma unroll
            for (int e = 0; e < 8; ++e) {
                const int k = k0 + e;
                a[e] = (k < F1) ? (_Float16)arow[k] : (_Float16)0.f;
                b[e] = (k < F1) ? (_Float16)brow[k] : (_Float16)0.f;
            }
        }
        acc = __builtin_amdgcn_mfma_f32_16x16x32_f16(a, b, acc, 0, 0, 0);
    }
    if (lr < 10) {
        #pragma unroll
        for (int r = 0; r < 4; ++r) {
            const long long m = row0 + kg * 4 + r;
            pot3[m * 10 + lr] = acc[r];
        }
    }
}

// ------------------------------------------------------------------
// k_winner: winner-take-all per batch, faithful to reference algebra.
// ------------------------------------------------------------------
__global__ __launch_bounds__(256)
void k_winner(const float* __restrict__ pot3, float* __restrict__ outCls, int nB)
{
    const int b = blockIdx.x * 256 + threadIdx.x;
    if (b >= nB) return;
    const float* p = pot3 + (long long)b * 150 + 140;   // t = 14 row

    float pv[10], s[10];
    float mv = 0.f;   // trunc.max includes the zero entries at t != 14
    #pragma unroll
    for (int g = 0; g < 10; ++g) {
        const float v = p[g];
        pv[g] = v;
        s[g]  = (v > 0.f) ? 1.f : ((v < 0.f) ? -1.f : 0.f);
        mv = fmaxf(mv, s[g] * v);
    }
    const float vbig = mv * 15.f;
    float bm = -INFINITY; int bi = 0;
    #pragma unroll
    for (int g = 0; g < 10; ++g) {
        const float tot = s[g] * pv[g] + s[g] * vbig;
        if (tot > bm) { bm = tot; bi = g; }   // strict > keeps first index
    }
    outCls[b] = (bm != 0.f) ? (float)bi : -1.f;
}

// ------------------------------------------------------------------
extern "C" void kernel_launch(void* const* d_in, const int* in_sizes, int n_in,
                              void* d_out, int out_size, void* d_ws, size_t ws_size,
                              hipStream_t stream)
{
    const float* inp = (const float*)d_in[0];
    const float* w1  = (const float*)d_in[1];
    const float* w3  = (const float*)d_in[2];

    float* out  = (float*)d_out;
    float* spk1 = out;
    float* thr1 = out + 30720000LL;
    float* pot3 = out + 61440000LL;
    float* cls  = out + 62054400LL;

    // Pre-split weight scratch: 2*25*32768 = 1638400 B. Prefer d_ws; else
    // borrow the pot3 region (read-only in conv1; conv3 overwrites it).
    float* scratch = (ws_size >= 1638400) ? (float*)d_ws : pot3;

    k_prep  <<<400, 256, 0, stream>>>(w1, scratch);
    k_conv1 <<<960, 512, 0, stream>>>(inp, scratch, spk1, thr1);
    k_conv3 <<<960, 256, 0, stream>>>(spk1, w3, pot3);
    k_winner<<<16,  256, 0, stream>>>(pot3, cls, 4096);
}